// Round 1
// baseline (949.132 us; speedup 1.0000x reference)
//
#include <hip/hip_runtime.h>
#include <hip/hip_bf16.h>

// Fused attention: scores = QK*scale + prev ; W = softmax(scores)*mask ; O = W V
// Outputs concatenated: [O (4,16,1024,64)][W (4,16,1024,1024)][S (4,16,1024,1024)]
//
// Block = 16 q-rows x full 1024 s for one (b,h). 4 waves split s into 256-col
// quarters. GEMM1/GEMM2 via mfma_f32_16x16x32_bf16; scale=0.125 folded into
// bf16(Q) exactly (power of two). No max-subtraction (|scores| < ~16, exp safe
// in fp32). W round-trips LDS (bf16) to convert C-layout -> A-operand layout.

#define QL 1024
#define SL 1024
#define HD 64

typedef __attribute__((ext_vector_type(8))) short bf16x8;
typedef __attribute__((ext_vector_type(4))) float f32x4;

__device__ __forceinline__ short f2bf(float f) {
    union { float f; unsigned u; } v; v.f = f;
    unsigned r = v.u + 0x7FFFu + ((v.u >> 16) & 1u);   // RNE
    return (short)(r >> 16);
}

__global__ __launch_bounds__(256) void
_ScaledDotProductAttention_Weighted_kernel(
    const float* __restrict__ q, const float* __restrict__ k,
    const float* __restrict__ v, const float* __restrict__ prev,
    const float* __restrict__ mask, const float* __restrict__ scale_p,
    float* __restrict__ out)
{
    const int WSTR = SL + 8;                  // bf16 elements, keeps b128 16B-aligned
    __shared__ short wbuf[16 * (SL + 8)];     // 33,024 B
    __shared__ float red[4 * 16];             // per-wave row-sum partials

    const int tid  = threadIdx.x;
    const int w    = tid >> 6;                // wave 0..3 -> s in [256w, 256w+256)
    const int lane = tid & 63;
    const int quad = lane >> 4;               // 0..3
    const int lp   = lane & 15;               // 0..15

    const int blk = blockIdx.x;
    const int bh  = blk >> 6;                 // 0..63  (b*16+h)
    const int qt  = blk & 63;                 // q-tile 0..63
    const int h   = bh & 15;
    const int q0  = qt * 16;

    const float scale = scale_p[0];           // 64^-0.5 = 0.125 exactly

    const float* Qb = q    + (size_t)bh * QL * HD + (size_t)q0 * HD;
    const float* Kb = k    + (size_t)bh * HD * SL;                    // [d][s]
    const float* Vb = v    + (size_t)bh * SL * HD;                    // [s][d]
    const float* Pb = prev + (size_t)bh * QL * SL + (size_t)q0 * SL;
    const float* Mb = mask + (size_t)h  * QL * SL + (size_t)q0 * SL;

    float* Ob   = out            + (size_t)bh * QL * HD + (size_t)q0 * HD;
    float* Wout = out + 4194304  + (size_t)bh * QL * SL + (size_t)q0 * SL;
    float* Sout = out + 71303168 + (size_t)bh * QL * SL + (size_t)q0 * SL;

    // ---- A fragments: bf16(Q * scale).  A[m=lp][k = ks*32 + quad*8 + j]
    bf16x8 aq[2];
#pragma unroll
    for (int ks = 0; ks < 2; ++ks) {
        const float* qp = Qb + (size_t)lp * HD + ks * 32 + quad * 8;
#pragma unroll
        for (int j = 0; j < 8; ++j) aq[ks][j] = f2bf(qp[j] * scale);
    }

    // ---- GEMM1: S = Q K * scale + prev, 16 tiles of 16 s-cols per wave
    const int s0 = 256 * w;
    f32x4 acc[16];
    // C-init from prev; C/D layout: col = lp, row = quad*4 + r
#pragma unroll
    for (int t = 0; t < 16; ++t) {
#pragma unroll
        for (int r = 0; r < 4; ++r)
            acc[t][r] = Pb[(size_t)(quad * 4 + r) * SL + s0 + 16 * t + lp];
    }
#pragma unroll
    for (int ks = 0; ks < 2; ++ks) {
#pragma unroll
        for (int t = 0; t < 16; ++t) {
            // B[k = quad*8+j][n = lp] = K[d = ks*32+quad*8+j][s0+16t+lp]
            bf16x8 bk;
            const float* kp = Kb + (size_t)(ks * 32 + quad * 8) * SL + s0 + 16 * t + lp;
#pragma unroll
            for (int j = 0; j < 8; ++j) bk[j] = f2bf(kp[(size_t)j * SL]);
            acc[t] = __builtin_amdgcn_mfma_f32_16x16x32_bf16(aq[ks], bk, acc[t], 0, 0, 0);
        }
    }

    // ---- store scores, exp in place, per-lane partial row sums
    float lsum[4] = {0.f, 0.f, 0.f, 0.f};
#pragma unroll
    for (int t = 0; t < 16; ++t) {
#pragma unroll
        for (int r = 0; r < 4; ++r) {
            float sv = acc[t][r];
            Sout[(size_t)(quad * 4 + r) * SL + s0 + 16 * t + lp] = sv;
            float e = __expf(sv);          // |sv| < ~16, no overflow; max-sub skipped
            acc[t][r] = e;
            lsum[r] += e;
        }
    }
    // reduce across the 16 lanes of each quad (row lives in one quad per wave)
#pragma unroll
    for (int r = 0; r < 4; ++r) {
        float s = lsum[r];
        s += __shfl_xor(s, 1);  s += __shfl_xor(s, 2);
        s += __shfl_xor(s, 4);  s += __shfl_xor(s, 8);
        lsum[r] = s;
    }
    if (lp == 0) {
#pragma unroll
        for (int r = 0; r < 4; ++r) red[w * 16 + quad * 4 + r] = lsum[r];
    }
    __syncthreads();
    float rinv[4];
#pragma unroll
    for (int r = 0; r < 4; ++r) {
        float s = red[0 * 16 + quad * 4 + r] + red[1 * 16 + quad * 4 + r]
                + red[2 * 16 + quad * 4 + r] + red[3 * 16 + quad * 4 + r];
        rinv[r] = 1.0f / s;
    }

    // ---- weights = e * rinv * mask : store fp32, stash bf16 in LDS for GEMM2
#pragma unroll
    for (int t = 0; t < 16; ++t) {
#pragma unroll
        for (int r = 0; r < 4; ++r) {
            int row = quad * 4 + r;
            int col = s0 + 16 * t + lp;
            float wv = acc[t][r] * rinv[r] * Mb[(size_t)row * SL + col];
            Wout[(size_t)row * SL + col] = wv;
            wbuf[row * WSTR + col] = f2bf(wv);
        }
    }
    __syncthreads();

    // ---- GEMM2: O[16 x 16] per wave, d-cols [16w, 16w+16), K = 1024 (s)
    f32x4 oacc = {0.f, 0.f, 0.f, 0.f};
#pragma unroll 4
    for (int ks = 0; ks < 32; ++ks) {
        // A[m=lp][k = ks*32 + quad*8 + j] from wbuf (16B-aligned b128)
        bf16x8 aw = *(const bf16x8*)&wbuf[lp * WSTR + ks * 32 + quad * 8];
        // B[k][n=16w+lp] = V[s = ks*32+quad*8+j][d = 16w+lp]
        bf16x8 bv;
        const float* vp = Vb + (size_t)(ks * 32 + quad * 8) * HD + 16 * w + lp;
#pragma unroll
        for (int j = 0; j < 8; ++j) bv[j] = f2bf(vp[(size_t)j * HD]);
        oacc = __builtin_amdgcn_mfma_f32_16x16x32_bf16(aw, bv, oacc, 0, 0, 0);
    }
#pragma unroll
    for (int r = 0; r < 4; ++r)
        Ob[(size_t)(quad * 4 + r) * HD + 16 * w + lp] = oacc[r];
}

extern "C" void kernel_launch(void* const* d_in, const int* in_sizes, int n_in,
                              void* d_out, int out_size, void* d_ws, size_t ws_size,
                              hipStream_t stream) {
    const float* q     = (const float*)d_in[0];
    const float* k     = (const float*)d_in[1];
    const float* v     = (const float*)d_in[2];
    const float* prev  = (const float*)d_in[3];
    const float* mask  = (const float*)d_in[4];
    const float* scale = (const float*)d_in[5];
    float* out = (float*)d_out;

    // 64 (b*h) x 64 q-tiles of 16 rows
    _ScaledDotProductAttention_Weighted_kernel<<<dim3(4096), dim3(256), 0, stream>>>(
        q, k, v, prev, mask, scale, out);
}